// Round 13
// baseline (910.355 us; speedup 1.0000x reference)
//
#include <hip/hip_runtime.h>
#include <hip/hip_bf16.h>
#include <math.h>

#define T_LEN 4096
#define DIM   2048
#define NH    6
#define DK    256
#define DVh   512
#define KD    1536
#define VD    3072
#define CK    64
#define NCHK  (T_LEN / CK)
#define NFUSE 9472   // 1536(q)+1536(k)+3072(x)+3072(gate)+256(tg)

typedef __attribute__((ext_vector_type(8))) short bf16x8;
typedef __attribute__((ext_vector_type(4))) float f32x4;

#define AS1 __attribute__((address_space(1)))
#define AS3 __attribute__((address_space(3)))

__device__ __forceinline__ float silu_f(float v){ return v / (1.f + __expf(-v)); }

__device__ __forceinline__ unsigned short f2bf(float f) {
  unsigned int u = __float_as_uint(f);
  unsigned int r = u + 0x7FFFu + ((u >> 16) & 1u);
  return (unsigned short)(r >> 16);
}
__device__ __forceinline__ float bf2f(unsigned short s) {
  return __uint_as_float(((unsigned int)s) << 16);
}

// LDS-only barrier: drains lgkmcnt but leaves global loads/stores in flight.
__device__ __forceinline__ void bar_lds() {
  __builtin_amdgcn_sched_barrier(0);
  asm volatile("s_waitcnt lgkmcnt(0)" ::: "memory");
  __builtin_amdgcn_s_barrier();
  __builtin_amdgcn_sched_barrier(0);
}

// ---------------- cast fp32 -> bf16 ----------------
__global__ __launch_bounds__(256) void cast_bf16(
    const float* __restrict__ in, unsigned short* __restrict__ out)
{
  int i = blockIdx.x * 256 + threadIdx.x;
  float4 v4 = ((const float4*)in)[i];
  ushort4 o4;
  o4.x = f2bf(v4.x); o4.y = f2bf(v4.y); o4.z = f2bf(v4.z); o4.w = f2bf(v4.w);
  ((ushort4*)out)[i] = o4;
}

// ---------------- R10: ALL weight transposes in ONE launch ----------------
__global__ __launch_bounds__(256) void tcast_all(
    const float* __restrict__ Wq, const float* __restrict__ Wk,
    const float* __restrict__ Wv, const float* __restrict__ Wg,
    const float* __restrict__ g1, const float* __restrict__ Wo,
    unsigned short* __restrict__ wTall, unsigned short* __restrict__ wT)
{
  int id = blockIdx.x;
  const float* in; unsigned short* out; int R, Cn, nbx;
  if (id < 3072)       { in = Wq; out = wTall;                          R = 2048; Cn = 1536; nbx = 48; }
  else if (id < 6144)  { in = Wk; out = wTall + (size_t)1536 * 2048;    R = 2048; Cn = 1536; nbx = 48; id -= 3072; }
  else if (id < 12288) { in = Wv; out = wTall + (size_t)3072 * 2048;    R = 2048; Cn = 3072; nbx = 96; id -= 6144; }
  else if (id < 18432) { in = Wg; out = wTall + (size_t)6144 * 2048;    R = 2048; Cn = 3072; nbx = 96; id -= 12288; }
  else if (id < 18944) { in = g1; out = wTall + (size_t)9216 * 2048;    R = 2048; Cn = 256;  nbx = 8;  id -= 18432; }
  else                 { in = Wo; out = wT;                             R = 3072; Cn = 2048; nbx = 64; id -= 18944; }
  int bx = (id % nbx) * 32, by = (id / nbx) * 32;
  __shared__ float tile[32][33];
  int tx = threadIdx.x & 31, ty = threadIdx.x >> 5;
#pragma unroll
  for (int i = 0; i < 32; i += 8)
    tile[ty + i][tx] = in[(size_t)(by + ty + i) * Cn + bx + tx];
  __syncthreads();
#pragma unroll
  for (int i = 0; i < 32; i += 8)
    out[(size_t)(bx + ty + i) * R + by + tx] = f2bf(tile[tx][ty + i]);
}

// ======== R7/R8 pipelined 128^2 GEMM core (BK=64, dbuf, counted vmcnt, T2 swizzle)
#define PSTAGE(Amat, Bmat, bufi, t_, Aptr, Bptr, Kk) do { \
    int k0_ = (t_) << 6; \
    _Pragma("unroll") \
    for (int i_ = 0; i_ < 4; ++i_) { \
      int c_ = threadIdx.x + 256 * i_; \
      int ks_ = c_ >> 9, row_ = (c_ >> 2) & 127, pc_ = c_ & 3; \
      int pcs_ = pc_ ^ ((row_ >> 1) & 3); \
      int gc_ = k0_ + ks_ * 32 + pcs_ * 8; \
      __builtin_amdgcn_global_load_lds( \
          (const AS1 unsigned int*)(Aptr + (size_t)(bm + row_) * (Kk) + gc_), \
          (AS3 unsigned int*)(&Amat[bufi][0] + c_ * 8), 16, 0, 0); \
      __builtin_amdgcn_global_load_lds( \
          (const AS1 unsigned int*)(Bptr + (size_t)(bn + row_) * (Kk) + gc_), \
          (AS3 unsigned int*)(&Bmat[bufi][0] + c_ * 8), 16, 0, 0); \
    } } while (0)

#define PGEMM_LOOP(Amat, Bmat, Aptr, Bptr, Kk, NTt) do { \
    PSTAGE(Amat, Bmat, 0, 0, Aptr, Bptr, Kk); \
    PSTAGE(Amat, Bmat, 1, 1, Aptr, Bptr, Kk); \
    __builtin_amdgcn_sched_barrier(0); \
    asm volatile("s_waitcnt vmcnt(8)" ::: "memory"); \
    __builtin_amdgcn_s_barrier(); \
    __builtin_amdgcn_sched_barrier(0); \
    const int slot_ = (kq ^ ((fr >> 1) & 3)) * 8; \
    for (int t = 0; t < (NTt); ++t) { \
      const unsigned short* as_ = &Amat[t & 1][0]; \
      const unsigned short* bs_ = &Bmat[t & 1][0]; \
      bf16x8 af_[2][4], bf_[2][4]; \
      _Pragma("unroll") \
      for (int ks_ = 0; ks_ < 2; ++ks_) { \
        _Pragma("unroll") \
        for (int i_ = 0; i_ < 4; ++i_) { \
          af_[ks_][i_] = *(const bf16x8*)(as_ + ks_ * 4096 + (wm + i_ * 16 + fr) * 32 + slot_); \
          bf_[ks_][i_] = *(const bf16x8*)(bs_ + ks_ * 4096 + (wn + i_ * 16 + fr) * 32 + slot_); \
        } } \
      __builtin_amdgcn_s_setprio(1); \
      _Pragma("unroll") \
      for (int i_ = 0; i_ < 4; ++i_) \
        _Pragma("unroll") \
        for (int j_ = 0; j_ < 4; ++j_) \
          acc[i_][j_] = __builtin_amdgcn_mfma_f32_16x16x32_bf16(af_[0][i_], bf_[0][j_], acc[i_][j_], 0, 0, 0); \
      __builtin_amdgcn_s_setprio(0); \
      bar_lds(); \
      if (t + 2 < (NTt)) PSTAGE(Amat, Bmat, t & 1, t + 2, Aptr, Bptr, Kk); \
      __builtin_amdgcn_s_setprio(1); \
      _Pragma("unroll") \
      for (int i_ = 0; i_ < 4; ++i_) \
        _Pragma("unroll") \
        for (int j_ = 0; j_ < 4; ++j_) \
          acc[i_][j_] = __builtin_amdgcn_mfma_f32_16x16x32_bf16(af_[1][i_], bf_[1][j_], acc[i_][j_], 0, 0, 0); \
      __builtin_amdgcn_s_setprio(0); \
      __builtin_amdgcn_sched_barrier(0); \
      if (t + 2 < (NTt)) { asm volatile("s_waitcnt vmcnt(8)" ::: "memory"); } \
      else               { asm volatile("s_waitcnt vmcnt(0)" ::: "memory"); } \
      __builtin_amdgcn_s_barrier(); \
      __builtin_amdgcn_sched_barrier(0); \
    } } while (0)

// ---------------- generic pipelined GEMM (used for out-proj) ----------------
__global__ __launch_bounds__(256) void gemm_bt_bf16(
    const unsigned short* __restrict__ A, const unsigned short* __restrict__ BT,
    void* __restrict__ Cout, int M, int N, int K, int act)
{
  __shared__ unsigned short As[2][8192];
  __shared__ unsigned short Bs[2][8192];
  const int tid = threadIdx.x;
  const int bm = blockIdx.y * 128, bn = blockIdx.x * 128;
  const int lane = tid & 63, wave = tid >> 6;
  const int wm = (wave >> 1) * 64, wn = (wave & 1) * 64;
  const int fr = lane & 15, kq = lane >> 4;
  const int NT = K >> 6;

  f32x4 acc[4][4];
#pragma unroll
  for (int i = 0; i < 4; ++i)
#pragma unroll
    for (int j = 0; j < 4; ++j) acc[i][j] = (f32x4){0.f, 0.f, 0.f, 0.f};

  PGEMM_LOOP(As, Bs, A, BT, K, NT);

  if (act == 2) {
    unsigned short* C = (unsigned short*)Cout;
#pragma unroll
    for (int i = 0; i < 4; ++i) {
      int rbase = bm + wm + i * 16 + kq * 4;
#pragma unroll
      for (int r = 0; r < 4; ++r) {
        size_t rowoff = (size_t)(rbase + r) * N + bn + wn + fr;
#pragma unroll
        for (int j = 0; j < 4; ++j) C[rowoff + j * 16] = f2bf(acc[i][j][r]);
      }
    }
  } else {
    float* C = (float*)Cout;
#pragma unroll
    for (int i = 0; i < 4; ++i) {
      int rbase = bm + wm + i * 16 + kq * 4;
#pragma unroll
      for (int r = 0; r < 4; ++r) {
        size_t rowoff = (size_t)(rbase + r) * N + bn + wn + fr;
#pragma unroll
        for (int j = 0; j < 4; ++j) {
          float v = acc[i][j][r];
          if (act == 1) v = silu_f(v);
          C[rowoff + j * 16] = v;
        }
      }
    }
  }
}

// ---------------- fused projection GEMM (R8 form: pipelined, grouped 1D grid) ----------------
__global__ __launch_bounds__(256) void gemm_fused(
    const unsigned short* __restrict__ A, const unsigned short* __restrict__ BT,
    float* __restrict__ Cq, float* __restrict__ Ck, float* __restrict__ Cx,
    unsigned short* __restrict__ Cg, float* __restrict__ Ct)
{
  __shared__ unsigned short As[2][8192];
  __shared__ unsigned short Bs[2][8192];
  const int tid = threadIdx.x;
  const int NPN = NFUSE / 128;           // 74
  const int GROUP = 8;
  const int npig = GROUP * NPN;          // 592
  const int pid = blockIdx.x;
  const int gid = pid / npig;
  const int pm = gid * GROUP + (pid % GROUP);
  const int pn = (pid % npig) / GROUP;
  const int bm = pm * 128, bn = pn * 128;
  const int lane = tid & 63, wave = tid >> 6;
  const int wm = (wave >> 1) * 64, wn = (wave & 1) * 64;
  const int fr = lane & 15, kq = lane >> 4;
  const int NT = DIM >> 6;               // 32

  f32x4 acc[4][4];
#pragma unroll
  for (int i = 0; i < 4; ++i)
#pragma unroll
    for (int j = 0; j < 4; ++j) acc[i][j] = (f32x4){0.f, 0.f, 0.f, 0.f};

  PGEMM_LOOP(As, Bs, A, BT, DIM, NT);

  // segment resolve (block-uniform)
  float* Fd = nullptr; unsigned short* Bd = nullptr;
  int strideN, cb, mode;   // mode: 0=fp32, 1=silu fp32, 2=bf16
  if (bn < 1536)      { Fd = Cq; strideN = 1536; cb = bn;        mode = 1; }
  else if (bn < 3072) { Fd = Ck; strideN = 1536; cb = bn - 1536; mode = 1; }
  else if (bn < 6144) { Fd = Cx; strideN = 3072; cb = bn - 3072; mode = 0; }
  else if (bn < 9216) { Bd = Cg; strideN = 3072; cb = bn - 6144; mode = 2; }
  else                { Fd = Ct; strideN = 256;  cb = bn - 9216; mode = 1; }

  if (mode == 2) {
#pragma unroll
    for (int i = 0; i < 4; ++i) {
      int rbase = bm + wm + i * 16 + kq * 4;
#pragma unroll
      for (int r = 0; r < 4; ++r) {
        size_t rowoff = (size_t)(rbase + r) * strideN + cb + wn + fr;
#pragma unroll
        for (int j = 0; j < 4; ++j) Bd[rowoff + j * 16] = f2bf(acc[i][j][r]);
      }
    }
  } else {
#pragma unroll
    for (int i = 0; i < 4; ++i) {
      int rbase = bm + wm + i * 16 + kq * 4;
#pragma unroll
      for (int r = 0; r < 4; ++r) {
        size_t rowoff = (size_t)(rbase + r) * strideN + cb + wn + fr;
#pragma unroll
        for (int j = 0; j < 4; ++j) {
          float v = acc[i][j][r];
          if (mode == 1) v = silu_f(v);
          Fd[rowoff + j * 16] = v;
        }
      }
    }
  }
}

// ---------------- dyn = tg @ gen_w2 ----------------
__global__ __launch_bounds__(256) void proj_dyn(
    const float* __restrict__ tg, const float* __restrict__ w2, float* __restrict__ dyn)
{
  int t = blockIdx.x, tid = threadIdx.x;
  float g = tg[(size_t)t * 256 + tid];
  float p[4];
#pragma unroll
  for (int j = 0; j < 4; ++j) p[j] = g * w2[tid * 4 + j];
#pragma unroll
  for (int j = 0; j < 4; ++j)
    for (int m = 32; m >= 1; m >>= 1) p[j] += __shfl_xor(p[j], m);
  __shared__ float red[4][4];
  if ((tid & 63) == 0) {
    int w = tid >> 6;
#pragma unroll
    for (int j = 0; j < 4; ++j) red[w][j] = p[j];
  }
  __syncthreads();
  if (tid < 4) dyn[(size_t)t * 4 + tid] = red[0][tid] + red[1][tid] + red[2][tid] + red[3][tid];
}

// ---------------- beta / raw decay log-gate g ----------------
__global__ __launch_bounds__(256) void proj_bg(
    const float* __restrict__ h, const float* __restrict__ Wb, const float* __restrict__ Wa,
    const float* __restrict__ A_log, const float* __restrict__ dt_bias,
    float* __restrict__ beta, float* __restrict__ gout)
{
  int t = blockIdx.x, tid = threadIdx.x;
  float pb[6], pa[6];
#pragma unroll
  for (int j = 0; j < 6; ++j) { pb[j] = 0.f; pa[j] = 0.f; }
  for (int d = tid; d < DIM; d += 256) {
    float hv = h[(size_t)t * DIM + d];
#pragma unroll
    for (int j = 0; j < 6; ++j) {
      pb[j] += hv * Wb[d * 6 + j];
      pa[j] += hv * Wa[d * 6 + j];
    }
  }
#pragma unroll
  for (int j = 0; j < 6; ++j)
    for (int m = 32; m >= 1; m >>= 1) { pb[j] += __shfl_xor(pb[j], m); pa[j] += __shfl_xor(pa[j], m); }
  __shared__ float rb[4][6], ra[4][6];
  if ((tid & 63) == 0) {
    int w = tid >> 6;
#pragma unroll
    for (int j = 0; j < 6; ++j) { rb[w][j] = pb[j]; ra[w][j] = pa[j]; }
  }
  __syncthreads();
  if (tid < 6) {
    int j = tid;
    float sb = rb[0][j] + rb[1][j] + rb[2][j] + rb[3][j];
    float sa = ra[0][j] + ra[1][j] + ra[2][j] + ra[3][j];
    beta[(size_t)t * 6 + j] = 1.f / (1.f + expf(-sb));
    float z = sa + dt_bias[j];
    float sp = (z > 20.f) ? z : log1pf(expf(z));
    gout[(size_t)t * 6 + j] = -expf(A_log[j]) * sp;   // raw log-gate (g < 0)
  }
}

// ---------------- causal dynamic conv + silu (8 timesteps/thread) ----------------
__global__ __launch_bounds__(256) void conv_kernel(
    const float* __restrict__ x, const float* __restrict__ dyn,
    const float* __restrict__ cw, float* __restrict__ v)
{
  int c = blockIdx.x * 256 + threadIdx.x;
  int t0 = blockIdx.y * 8;
  float4 w4 = ((const float4*)cw)[c];
  float xs[11];
#pragma unroll
  for (int i = 0; i < 11; ++i) {
    int t = t0 - 3 + i;
    xs[i] = (t >= 0) ? x[(size_t)t * VD + c] : 0.f;
  }
#pragma unroll
  for (int j = 0; j < 8; ++j) {
    int t = t0 + j;
    float4 dd = ((const float4*)dyn)[t];
    float acc = (w4.x + dd.x) * xs[j]
              + (w4.y + dd.y) * xs[j + 1]
              + (w4.z + dd.z) * xs[j + 2]
              + (w4.w + dd.w) * xs[j + 3];
    v[(size_t)t * VD + c] = silu_f(acc);
  }
}

// ---------------- P1: within-chunk inclusive cumsum of g, gamma = exp(c_end) ----------------
__global__ __launch_bounds__(64) void cumsum_g(
    const float* __restrict__ g, float* __restrict__ c, float* __restrict__ gammas)
{
  int ch = blockIdx.x, h = blockIdx.y;
  int t0 = ch * CK;
  int lane = threadIdx.x;
  float cum = g[(size_t)(t0 + lane) * 6 + h];
  for (int off = 1; off < 64; off <<= 1) {
    float n = __shfl_up(cum, off);
    if (lane >= off) cum += n;
  }
  c[(size_t)h * T_LEN + t0 + lane] = cum;
  if (lane == 63) gammas[h * NCHK + ch] = __expf(cum);
}

// ---------------- fused l2norm + Kbar/Qbar scale ----------------
__global__ __launch_bounds__(384) void l2scale(
    float* __restrict__ q, float* __restrict__ k, const float* __restrict__ c,
    unsigned short* __restrict__ Qb, unsigned short* __restrict__ Kb)
{
  int t = blockIdx.x;
  int h = threadIdx.x >> 6, lane = threadIdx.x & 63;
  size_t off = (size_t)t * KD + h * 256 + lane * 4;
  float4 qv = *(const float4*)(q + off);
  float4 kv = *(const float4*)(k + off);
  float sq = qv.x*qv.x + qv.y*qv.y + qv.z*qv.z + qv.w*qv.w;
  float sk = kv.x*kv.x + kv.y*kv.y + kv.z*kv.z + kv.w*kv.w;
  for (int m = 32; m >= 1; m >>= 1) { sq += __shfl_xor(sq, m); sk += __shfl_xor(sk, m); }
  float rq = rsqrtf(sq + 1e-6f) * 0.0625f;   // fold DK^-0.5
  float rk = rsqrtf(sk + 1e-6f);
  qv.x *= rq; qv.y *= rq; qv.z *= rq; qv.w *= rq;
  kv.x *= rk; kv.y *= rk; kv.z *= rk; kv.w *= rk;
  *(float4*)(q + off) = qv;
  *(float4*)(k + off) = kv;
  float w1 = __expf(c[(size_t)h * T_LEN + t]);
  ushort4 qo, ko;
  qo.x = f2bf(w1 * qv.x); qo.y = f2bf(w1 * qv.y); qo.z = f2bf(w1 * qv.z); qo.w = f2bf(w1 * qv.w);
  ko.x = f2bf(w1 * kv.x); ko.y = f2bf(w1 * kv.y); ko.z = f2bf(w1 * kv.z); ko.w = f2bf(w1 * kv.w);
  *(ushort4*)(Qb + off) = qo;
  *(ushort4*)(Kb + off) = ko;
}

// ---------------- P2b: KhT[h][ch][kk][tt] = exp(c_end - c_t) * k[t][kk]  (bf16) ----------------
// LDS-transpose form (R9): coalesced loads -> [64][258] tile -> coalesced writes.
__global__ __launch_bounds__(256) void make_khT(
    const float* __restrict__ k, const float* __restrict__ c,
    unsigned short* __restrict__ KhT)
{
  int ch = blockIdx.x, h = blockIdx.y;
  int t0 = ch * CK;
  int tid = threadIdx.x;
  __shared__ unsigned short tile[64][258];
  __shared__ float ws[64];
  if (tid < 64) {
    float cend = c[(size_t)h * T_LEN + t0 + 63];
    ws[tid] = __expf(cend - c[(size_t)h * T_LEN + t0 + tid]);
  }
  __syncthreads();
#pragma unroll 8
  for (int rr = 0; rr < 64; ++rr) {
    float kv = k[(size_t)(t0 + rr) * KD + h * 256 + tid];
    tile[rr][tid] = f2bf(ws[rr] * kv);
  }
  __syncthreads();
  size_t obase = ((size_t)(h * NCHK + ch)) * DK * CK;
  int tt = tid & 63, kr = tid >> 6;
#pragma unroll 8
  for (int kb = 0; kb < 64; ++kb) {
    int kk = kb * 4 + kr;
    KhT[obase + (size_t)kk * CK + tt] = tile[tt][kk];
  }
}

// ---------------- P3: per (h,chunk): L, P via MFMA ----------------
__global__ __launch_bounds__(256) void chunk_lp(
    const float* __restrict__ q, const float* __restrict__ k,
    const float* __restrict__ c, const float* __restrict__ beta,
    float* __restrict__ Lg, unsigned short* __restrict__ Pm)
{
  const int ch = blockIdx.x, h = blockIdx.y;
  const int t0 = ch * CK;
  const int tid = threadIdx.x;
  const int w = tid >> 6, lane = tid & 63, fr = lane & 15, kq = lane >> 4;
  __shared__ unsigned short kb[64][264];
  __shared__ unsigned short qb[64][264];
  __shared__ float cs[64], bs[64];
#pragma unroll
  for (int i = 0; i < 16; ++i) {
    int fi = tid + i * 256;
    int r = fi >> 6, d4 = fi & 63;
    float4 kv = *(const float4*)(k + (size_t)(t0 + r) * KD + h * 256 + d4 * 4);
    float4 qv = *(const float4*)(q + (size_t)(t0 + r) * KD + h * 256 + d4 * 4);
    ushort4 k4, q4;
    k4.x = f2bf(kv.x); k4.y = f2bf(kv.y); k4.z = f2bf(kv.z); k4.w = f2bf(kv.w);
    q4.x = f2bf(qv.x); q4.y = f2bf(qv.y); q4.z = f2bf(qv.z); q4.w = f2bf(qv.w);
    *(ushort4*)&kb[r][d4 * 4] = k4;
    *(ushort4*)&qb[r][d4 * 4] = q4;
  }
  if (tid < 64) {
    cs[tid] = c[(size_t)h * T_LEN + t0 + tid];
    bs[tid] = beta[(size_t)(t0 + tid) * 6 + h];
  }
  __syncthreads();

  f32x4 akk[4], aqk[4];
#pragma unroll
  for (int j = 0; j < 4; ++j) { akk[j] = (f32x4){0,0,0,0}; aqk[j] = (f32x4){0,0,0,0}; }
#pragma unroll
  for (int kt = 0; kt < 8; ++kt) {
    bf16x8 ak = *(const bf16x8*)&kb[16 * w + fr][kt * 32 + kq * 8];
    bf16x8 aq = *(const bf16x8*)&qb[16 * w + fr][kt * 32 + kq * 8];
#pragma unroll
    for (int j = 0; j < 4; ++j) {
      bf16x8 b = *(const bf16x8*)&kb[j * 16 + fr][kt * 32 + kq * 8];
      akk[j] = __builtin_amdgcn_mfma_f32_16x16x32_bf16(ak, b, akk[j], 0, 0, 0);
      aqk[j] = __builtin_amdgcn_mfma_f32_16x16x32_bf16(aq, b, aqk[j], 0, 0, 0);
    }
  }
  size_t base = ((size_t)(h * NCHK + ch)) * CK * CK;
#pragma unroll
  for (int j = 0; j < 4; ++j) {
#pragma unroll
    for (int r = 0; r < 4; ++r) {
      int t = 16 * w + kq * 4 + r, col = j * 16 + fr;
      float e = __expf(fminf(cs[t] - cs[col], 0.f));
      Lg[base + t * 64 + col] = (col < t) ? bs[t] * e * akk[j][r] : 0.f;
      Pm[base + t * 64 + col] = f2bf((col <= t) ? e * aqk[j][r] : 0.f);
    }
  }
}

// ---------------- P4: T' = (I+L)^{-1} diag(beta)  (bf16) ----------------
__global__ __launch_bounds__(64) void tri_inv(
    const float* __restrict__ Lg, const float* __restrict__ beta,
    unsigned short* __restrict__ Tm)
{
  const int ch = blockIdx.x, h = blockIdx.y;
  const size_t base = ((size_t)(h * NCHK + ch)) * CK * CK;
  const int j = threadIdx.x;
  __shared__ float Ll[64][65];
  __shared__ float Tl[64][65];
  for (int t = 0; t < 64; ++t) Ll[t][j] = Lg[base + t * 64 + j];
  __syncthreads();
  for (int t = 0; t < 64; ++t) {
    float s;
    if (j > t) s = 0.f;
    else if (j == t) s = 1.f;
    else {
      s = 0.f;
      for (int m = j; m < t; ++m) s -= Ll[t][m] * Tl[m][j];
    }
    Tl[t][j] = s;
  }
  float bj = beta[(size_t)(ch * 64 + j) * 6 + h];
  for (int t = 0; t < 64; ++t) Tm[base + t * 64 + j] = f2bf(Tl[t][j] * bj);
}

// ---------------- chunked gated delta-rule scan (MFMA, 8-wave) — R3 form ----------------
__global__ __launch_bounds__(512, 2) void scan_chunk(
    const unsigned short* __restrict__ Kb,   // [T][KD] Kbar
    const unsigned short* __restrict__ Qb,   // [T][KD] Qbar
    const unsigned short* __restrict__ KhT,  // [H][NCHK][DK][CK]
    const unsigned short* __restrict__ Tm,   // [H][NCHK][CK][CK]
    const unsigned short* __restrict__ Pm,   // [H][NCHK][CK][CK]
    const float* __restrict__ gammas,        // [H][NCHK]
    float* __restrict__ VO)                  // [T][VD]: V in, O out (in place)
{
  const int h = blockIdx.y, sl = blockIdx.x;
  const int tid = threadIdx.x;
  const int w = tid >> 6, lane = tid & 63;
  const int tw = w & 3, kg = w >> 2;
  const int fr = lane & 15, kq = lane >> 4;

  __shared__ unsigned short S0h[16][264];
  __shared__ unsigned short S0l[16][264];
  __shared__ unsigned short XT[16][72];
  __shared__ unsigned short DVT[16][72];
  __shared__ float PY[2][4][16][20];   // partial Y, [kg][tw][fr][kq*4+r]
  __shared__ float PO[2][4][16][20];   // partial O

  f32x4 st[2];
  st[0] = (f32x4){0.f, 0.f, 0.f, 0.f};
  st[1] = (f32x4){0.f, 0.f, 0.f, 0.f};

  const int colg = h * DVh + sl * 16 + fr;
  const size_t hc0 = (size_t)h * NCHK;

  // zero-init S0 staging (cols 0..255 are the ones read)
  {
    int zr = tid >> 5;          // 0..15
    int zc = (tid & 31) * 8;    // 0..248
    ushort4 z; z.x = 0; z.y = 0; z.z = 0; z.w = 0;
    *(ushort4*)&S0h[zr][zc]     = z;
    *(ushort4*)&S0h[zr][zc + 4] = z;
    *(ushort4*)&S0l[zr][zc]     = z;
    *(ushort4*)&S0l[zr][zc + 4] = z;
  }

  bf16x8 kfA[4], kfB[4], qfA[4], qfB[4];
  float vlA[4], vlB[4];

#define PREF(KF, QF, VL, chn) do { \
    const unsigned short* kr_ = Kb + (size_t)((chn) * CK + 16 * tw + fr) * KD + h * 256 + kg * 128 + kq * 8; \
    const unsigned short* qr_ = Qb + (size_t)((chn) * CK + 16 * tw + fr) * KD + h * 256 + kg * 128 + kq * 8; \
    _Pragma("unroll") \
    for (int kt = 0; kt < 4; ++kt) { \
      KF[kt] = *(const bf16x8*)(kr_ + kt * 32); \
      QF[kt] = *(const bf16x8*)(qr_ + kt * 32); } \
    if (kg == 0) { \
      _Pragma("unroll") \
      for (int r = 0; r < 4; ++r) VL[r] = VO[(size_t)((chn) * CK + 16 * tw + kq * 4 + r) * VD + colg]; } \
  } while (0)

#define BODY(chx, KF, QF, VL, KFN, QFN, VLN) do { \
    const int ch_ = (chx); \
    const int t0_ = ch_ * CK; \
    const size_t cb_ = hc0 + ch_; \
    /* tpf: kg0 = T' rows (for DV), kg1 = P rows (for O) */ \
    bf16x8 tpf[2]; \
    { const unsigned short* b_ = (kg == 0 ? Tm : Pm) + (cb_ * CK + 16 * tw + fr) * CK + kq * 8; \
      tpf[0] = *(const bf16x8*)(b_); tpf[1] = *(const bf16x8*)(b_ + 32); } \
    bf16x8 hfr[2][2]; \
    _Pragma("unroll") \
    for (int i = 0; i < 2; ++i) { \
      const unsigned short* hr_ = KhT + (cb_ * DK + 32 * w + 16 * i + fr) * CK + kq * 8; \
      hfr[i][0] = *(const bf16x8*)(hr_); hfr[i][1] = *(const bf16x8*)(hr_ + 32); } \
    const float gam_ = gammas[cb_]; \
    { const int chn_ = (ch_ + 1 < NCHK) ? ch_ + 1 : ch_; PREF(KFN, QFN, VLN, chn_); } \
    /* P1: partial Y/O over this wave's half of DK (4 kt) */ \
    f32x4 yt, ot; \
    { f32x4 yh = (f32x4){0.f,0.f,0.f,0.f}, yl = yh, oh = yh, ol = yh; \
      __builtin_amdgcn_s_setprio(1); \
      _Pragma("unroll") \
      for (int kt = 0; kt < 4; ++kt) { \
        const int ka_ = (kg * 4 + kt) * 32 + kq * 8; \
        bf16x8 bh_ = *(const bf16x8*)&S0h[fr][ka_]; \
        bf16x8 bl_ = *(const bf16x8*)&S0l[fr][ka_]; \
        yh = __builtin_amdgcn_mfma_f32_16x16x32_bf16(KF[kt], bh_, yh, 0, 0, 0); \
        yl = __builtin_amdgcn_mfma_f32_16x16x32_bf16(KF[kt], bl_, yl, 0, 0, 0); \
        oh = __builtin_amdgcn_mfma_f32_16x16x32_bf16(QF[kt], bh_, oh, 0, 0, 0); \
        ol = __builtin_amdgcn_mfma_f32_16x16x32_bf16(QF[kt], bl_, ol, 0, 0, 0); } \
      __builtin_amdgcn_s_setprio(0); \
      yt = yh + yl; ot = oh + ol; } \
    *(f32x4*)&PY[kg][tw][fr][kq * 4] = yt; \
    *(f32x4*)&PO[kg][tw][fr][kq * 4] = ot; \
    bar_lds();   /* B1: partials visible */ \
    if (kg == 0) { \
      f32x4 yo = *(const f32x4*)&PY[1][tw][fr][kq * 4]; \
      ushort4 x4; \
      x4.x = f2bf(VL[0] - (yt[0] + yo[0])); \
      x4.y = f2bf(VL[1] - (yt[1] + yo[1])); \
      x4.z = f2bf(VL[2] - (yt[2] + yo[2])); \
      x4.w = f2bf(VL[3] - (yt[3] + yo[3])); \
      *(ushort4*)&XT[fr][16 * tw + kq * 4] = x4; \
    } else { \
      f32x4 oo = *(const f32x4*)&PO[0][tw][fr][kq * 4]; \
      ot[0] += oo[0]; ot[1] += oo[1]; ot[2] += oo[2]; ot[3] += oo[3]; } \
    bar_lds();   /* B2: XT visible */ \
    /* P2: DV = T' X (kg0 only) */ \
    if (kg == 0) { \
      f32x4 d = (f32x4){0.f,0.f,0.f,0.f}; \
      bf16x8 b0_ = *(const bf16x8*)&XT[fr][kq * 8]; \
      bf16x8 b1_ = *(const bf16x8*)&XT[fr][32 + kq * 8]; \
      d = __builtin_amdgcn_mfma_f32_16x16x32_bf16(tpf[0], b0_, d, 0, 0, 0); \
      d = __builtin_amdgcn_mfma_f32_16x16x32_bf16(tpf[1], b1_, d, 0, 0, 0); \
      ushort4 d4; \
      d4.x = f2bf(d[0]); d4.y = f2bf(d[1]); d4.z = f2bf(d[2]); d4.w = f2bf(d[3]); \
      *(ushort4*)&DVT[fr][16 * tw + kq * 4] = d4; } \
    bar_lds();   /* B3: DVT visible */ \
    /* P3: O-store (kg1), state update + S0 staging (all) */ \
    { bf16x8 dv0_ = *(const bf16x8*)&DVT[fr][kq * 8]; \
      bf16x8 dv1_ = *(const bf16x8*)&DVT[fr][32 + kq * 8]; \
      if (kg == 1) { \
        f32x4 op = (f32x4){0.f,0.f,0.f,0.f}; \
        op = __builtin_amdgcn_mfma_f32_16x16x32_bf16(tpf[0], dv0_, op, 0, 0, 0); \
        op = __builtin_amdgcn_mfma_f32_16x16x32_bf16(tpf[1], dv1_, op, 0, 0, 0); \
        _Pragma("unroll") \
        for (int r = 0; r < 4; ++r) \
          VO[(size_t)(t0_ + 16 * tw + kq * 4 + r) * VD + colg] = ot[r] + op[r]; } \
      __builtin_amdgcn_s_setprio(1); \
      _Pragma("unroll") \
      for (int i = 0; i < 2; ++i) { \
        st[i][0] *= gam_; st[i][1] *= gam_; st[i][2] *= gam_; st[i][3] *= gam_; \
        st[i] = __builtin_amdgcn_mfma_f32_16x16x32_bf16(hfr[i][0], dv0_, st[i], 0, 0, 0); \
        st[i] = __builtin_amdgcn_mfma_f32_16x16x32_bf16(hfr[i][1], dv1_, st[i], 0, 0, 0); \
        ushort4 hi4, lo4; \
        { float s0 = st[i][0], s1 = st[i][1], s2 = st[i][2], s3 = st[i][3]; \
          hi4.x = f2bf(s0); lo4.x = f2bf(s0 - bf2f(hi4.x)); \
          hi4.y = f2bf(s1); lo4.y = f2bf(s1 - bf2f(hi4.y)); \
          hi4.z = f2bf(s2); lo4.z = f2bf(s2 - bf2f(hi4.z)); \
          hi4.w = f2bf(s3); lo4.w = f2bf(s3 - bf2f(hi4.w)); } \
        *(ushort4*)&S0h[fr][32 * w + 16 * i + kq * 4] = hi4; \
        *(ushort4*)&S0l[fr][32 * w + 16 * i + kq * 4] = lo4; } \
      __builtin_amdgcn_s_setprio(0); } \
    bar_lds();   /* B4: S0 visible for next chunk */ \
  } while (0)

  PREF(kfA, qfA, vlA, 0);
  __syncthreads();   // covers the LDS zero-init
  for (int ch = 0; ch < NCHK; ch += 2) {
    BODY(ch,     kfA, qfA, vlA, kfB, qfB, vlB);
    BODY(ch + 1, kfB, qfB, vlB, kfA, qfA, vlA);
  }
#undef BODY
#undef PREF
}

// ---------------- gated RMSNorm ----------------
__global__ __launch_bounds__(256) void norm_gate(
    const float* __restrict__ o, const unsigned short* __restrict__ gate,
    const float* __restrict__ nw, unsigned short* __restrict__ out)
{
  int th = blockIdx.x, tid = threadIdx.x;
  size_t base = (size_t)th * DVh;
  float x0 = o[base + tid], x1 = o[base + 256 + tid];
  float ss = x0 * x0 + x1 * x1;
  for (int m = 32; m >= 1; m >>= 1) ss += __shfl_xor(ss, m);
  __shared__ float red[4];
  if ((tid & 63) == 0) red[tid >> 6] = ss;
  __syncthreads();
  float rms = rsqrtf((red[0] + red[1] + red[2] + red[3]) * (1.f / 512.f) + 1e-5f);
  float g0 = bf2f(gate[base + tid]), g1 = bf2f(gate[base + 256 + tid]);
  out[base + tid]       = f2bf(x0 * rms * nw[tid]       * silu_f(g0));
  out[base + 256 + tid] = f2bf(x1 * rms * nw[tid + 256] * silu_f(g1));
}

extern "C" void kernel_launch(void* const* d_in, const int* in_sizes, int n_in,
                              void* d_out, int out_size, void* d_ws, size_t ws_size,
                              hipStream_t stream)
{
  const float* h       = (const float*)d_in[0];
  const float* Wq      = (const float*)d_in[1];
  const float* Wk      = (const float*)d_in[2];
  const float* Wv      = (const float*)d_in[3];
  const float* Wb      = (const float*)d_in[4];
  const float* Wa      = (const float*)d_in[5];
  const float* Wg      = (const float*)d_in[6];
  const float* Wo      = (const float*)d_in[7];
  const float* A_log   = (const float*)d_in[8];
  const float* dt_bias = (const float*)d_in[9];
  const float* conv_w  = (const float*)d_in[10];
  const float* gen_w1  = (const float*)d_in[11];
  const float* gen_w2  = (const float*)d_in[12];
  const float* norm_w  = (const float*)d_in[13];
  float* out = (float*)d_out;

  const size_t TK = (size_t)T_LEN * KD, TV = (size_t)T_LEN * VD, TD = (size_t)T_LEN * DIM;

  float* ws   = (float*)d_ws;
  float* q    = ws;
  float* k    = q    + TK;
  float* x    = k    + TK;          // h@Wv conv input; region later reused (see aliases)
  float* v    = x    + TV;          // conv out; O written in place by scan
  float* tg   = v    + TV;          // T*256
  float* dyn  = tg   + (size_t)T_LEN * 256;
  float* beta = dyn  + (size_t)T_LEN * 4;
  float* g    = beta + (size_t)T_LEN * 6;
  float* c    = g    + (size_t)T_LEN * 6;       // [H][T]
  float* gam  = c    + (size_t)NH * T_LEN;      // [H][NCHK]
  float* fend = gam  + 512;
  unsigned short* bh      = (unsigned short*)fend;          // T*DIM
  unsigned short* wT      = bh      + TD;                   // DIM*VD (used for Wo only)
  unsigned short* gate_bf = wT      + (size_t)DIM * VD;     // T*VD
  unsigned short* go_bf   = gate_bf + TV;                   // T*VD
  // aliases (lifetime-disjoint):
  unsigned short* Kb_s  = bh;                 // Kbar: bh dead after fused GEMM
  unsigned short* Qb_s  = (unsigned short*)x; // x region free after conv
  unsigned short* KhT_s = Qb_s + TK;
  unsigned short* Tm_s  = KhT_s + TK;         // H*NCHK*DK*CK == T*KD
  unsigned short* Pm_s  = Tm_s + (size_t)NH * NCHK * CK * CK;
  float* Lg = (float*)go_bf;                  // consumed before norm_gate writes go_bf
  // stacked B^T for fused GEMM: [9472][2048] bf16 = 38.8 MB; aliases v region
  // (50.3 MB) — used only before conv_kernel writes v.
  unsigned short* wTall = (unsigned short*)v;

  dim3 blk(256);
  cast_bf16<<<(TD / 4) / 256, blk, 0, stream>>>(h, bh);
  // ALL weight transposes (5 stacked projections + Wo) in one launch
  tcast_all<<<25088, blk, 0, stream>>>(Wq, Wk, Wv, Wg, gen_w1, Wo, wTall, wT);
  // one fused GEMM for q | k | x | gate | tg (1D grid, grouped block order)
  gemm_fused<<<dim3((NFUSE / 128) * (T_LEN / 128)), blk, 0, stream>>>(
      bh, wTall, q, k, x, gate_bf, tg);

  proj_bg<<<T_LEN, blk, 0, stream>>>(h, Wb, Wa, A_log, dt_bias, beta, g);
  cumsum_g<<<dim3(NCHK, NH), 64, 0, stream>>>(g, c, gam);
  proj_dyn<<<T_LEN, blk, 0, stream>>>(tg, gen_w2, dyn);
  conv_kernel<<<dim3(VD / 256, T_LEN / 8), blk, 0, stream>>>(x, dyn, conv_w, v);
  l2scale<<<T_LEN, 384, 0, stream>>>(q, k, c, Qb_s, Kb_s);

  make_khT<<<dim3(NCHK, NH), blk, 0, stream>>>(k, c, KhT_s);
  chunk_lp<<<dim3(NCHK, NH), blk, 0, stream>>>(q, k, c, beta, Lg, Pm_s);
  tri_inv<<<dim3(NCHK, NH), 64, 0, stream>>>(Lg, beta, Tm_s);

  scan_chunk<<<dim3(DVh / 16, NH), 512, 0, stream>>>(Kb_s, Qb_s, KhT_s, Tm_s, Pm_s, gam, v);

  norm_gate<<<T_LEN * NH, blk, 0, stream>>>(v, gate_bf, norm_w, go_bf);
  gemm_bt_bf16<<<dim3(DIM / 128, T_LEN / 128), blk, 0, stream>>>(go_bf, wT, out, T_LEN, DIM, VD, 0);
}

// Round 14
// 884.597 us; speedup vs baseline: 1.0291x; 1.0291x over previous
//
#include <hip/hip_runtime.h>
#include <hip/hip_bf16.h>
#include <math.h>

#define T_LEN 4096
#define DIM   2048
#define NH    6
#define DK    256
#define DVh   512
#define KD    1536
#define VD    3072
#define CK    64
#define NCHK  (T_LEN / CK)
#define NFUSE 9472   // 1536(q)+1536(k)+3072(x)+3072(gate)+256(tg)

typedef __attribute__((ext_vector_type(8))) short bf16x8;
typedef __attribute__((ext_vector_type(4))) float f32x4;

#define AS1 __attribute__((address_space(1)))
#define AS3 __attribute__((address_space(3)))

__device__ __forceinline__ float silu_f(float v){ return v / (1.f + __expf(-v)); }

__device__ __forceinline__ unsigned short f2bf(float f) {
  unsigned int u = __float_as_uint(f);
  unsigned int r = u + 0x7FFFu + ((u >> 16) & 1u);
  return (unsigned short)(r >> 16);
}
__device__ __forceinline__ float bf2f(unsigned short s) {
  return __uint_as_float(((unsigned int)s) << 16);
}

// LDS-only barrier: drains lgkmcnt but leaves global loads/stores in flight.
__device__ __forceinline__ void bar_lds() {
  __builtin_amdgcn_sched_barrier(0);
  asm volatile("s_waitcnt lgkmcnt(0)" ::: "memory");
  __builtin_amdgcn_s_barrier();
  __builtin_amdgcn_sched_barrier(0);
}

// ---------------- cast fp32 -> bf16 ----------------
__global__ __launch_bounds__(256) void cast_bf16(
    const float* __restrict__ in, unsigned short* __restrict__ out)
{
  int i = blockIdx.x * 256 + threadIdx.x;
  float4 v4 = ((const float4*)in)[i];
  ushort4 o4;
  o4.x = f2bf(v4.x); o4.y = f2bf(v4.y); o4.z = f2bf(v4.z); o4.w = f2bf(v4.w);
  ((ushort4*)out)[i] = o4;
}

// ---------------- R10: ALL weight transposes in ONE launch ----------------
__global__ __launch_bounds__(256) void tcast_all(
    const float* __restrict__ Wq, const float* __restrict__ Wk,
    const float* __restrict__ Wv, const float* __restrict__ Wg,
    const float* __restrict__ g1, const float* __restrict__ Wo,
    unsigned short* __restrict__ wTall, unsigned short* __restrict__ wT)
{
  int id = blockIdx.x;
  const float* in; unsigned short* out; int R, Cn, nbx;
  if (id < 3072)       { in = Wq; out = wTall;                          R = 2048; Cn = 1536; nbx = 48; }
  else if (id < 6144)  { in = Wk; out = wTall + (size_t)1536 * 2048;    R = 2048; Cn = 1536; nbx = 48; id -= 3072; }
  else if (id < 12288) { in = Wv; out = wTall + (size_t)3072 * 2048;    R = 2048; Cn = 3072; nbx = 96; id -= 6144; }
  else if (id < 18432) { in = Wg; out = wTall + (size_t)6144 * 2048;    R = 2048; Cn = 3072; nbx = 96; id -= 12288; }
  else if (id < 18944) { in = g1; out = wTall + (size_t)9216 * 2048;    R = 2048; Cn = 256;  nbx = 8;  id -= 18432; }
  else                 { in = Wo; out = wT;                             R = 3072; Cn = 2048; nbx = 64; id -= 18944; }
  int bx = (id % nbx) * 32, by = (id / nbx) * 32;
  __shared__ float tile[32][33];
  int tx = threadIdx.x & 31, ty = threadIdx.x >> 5;
#pragma unroll
  for (int i = 0; i < 32; i += 8)
    tile[ty + i][tx] = in[(size_t)(by + ty + i) * Cn + bx + tx];
  __syncthreads();
#pragma unroll
  for (int i = 0; i < 32; i += 8)
    out[(size_t)(bx + ty + i) * R + by + tx] = f2bf(tile[tx][ty + i]);
}

// ======== R14 pipelined 128^2 GEMM core (BK=64, dbuf, counted vmcnt, T2 swizzle)
// R14: staging addresses strength-reduced. The swizzled per-thread global base
// (4 A + 4 B pointers) is computed ONCE; consecutive staged tiles differ by
// exactly +64 elements, so each stage advances the pointers in place. Replaces
// ~55 VALU insts/tile/thread of address recompute with ~16 (VALUBusy was 40%
// alongside MfmaUtil 29% = issue-saturated; address math was on the path).
// Addresses generated are bit-identical to R8 (tile tt = #prior stage calls).
#define PSTG(Amat, Bmat, bufi) do { \
    _Pragma("unroll") \
    for (int i_ = 0; i_ < 4; ++i_) { \
      int c_ = threadIdx.x + 256 * i_; \
      __builtin_amdgcn_global_load_lds( \
          (const AS1 unsigned int*)agp_[i_], \
          (AS3 unsigned int*)(&Amat[bufi][0] + c_ * 8), 16, 0, 0); \
      __builtin_amdgcn_global_load_lds( \
          (const AS1 unsigned int*)bgp_[i_], \
          (AS3 unsigned int*)(&Bmat[bufi][0] + c_ * 8), 16, 0, 0); \
      agp_[i_] += 64; bgp_[i_] += 64; \
    } } while (0)

#define PGEMM_LOOP(Amat, Bmat, Aptr, Bptr, Kk, NTt) do { \
    const unsigned short* agp_[4]; \
    const unsigned short* bgp_[4]; \
    _Pragma("unroll") \
    for (int i_ = 0; i_ < 4; ++i_) { \
      int c_ = threadIdx.x + 256 * i_; \
      int ks_ = c_ >> 9, row_ = (c_ >> 2) & 127, pc_ = c_ & 3; \
      int pcs_ = pc_ ^ ((row_ >> 1) & 3); \
      int gc_ = ks_ * 32 + pcs_ * 8; \
      agp_[i_] = (Aptr) + (size_t)(bm + row_) * (Kk) + gc_; \
      bgp_[i_] = (Bptr) + (size_t)(bn + row_) * (Kk) + gc_; \
    } \
    PSTG(Amat, Bmat, 0); \
    PSTG(Amat, Bmat, 1); \
    __builtin_amdgcn_sched_barrier(0); \
    asm volatile("s_waitcnt vmcnt(8)" ::: "memory"); \
    __builtin_amdgcn_s_barrier(); \
    __builtin_amdgcn_sched_barrier(0); \
    const int slot_ = (kq ^ ((fr >> 1) & 3)) * 8; \
    for (int t = 0; t < (NTt); ++t) { \
      const unsigned short* as_ = &Amat[t & 1][0]; \
      const unsigned short* bs_ = &Bmat[t & 1][0]; \
      bf16x8 af_[2][4], bf_[2][4]; \
      _Pragma("unroll") \
      for (int ks_ = 0; ks_ < 2; ++ks_) { \
        _Pragma("unroll") \
        for (int i_ = 0; i_ < 4; ++i_) { \
          af_[ks_][i_] = *(const bf16x8*)(as_ + ks_ * 4096 + (wm + i_ * 16 + fr) * 32 + slot_); \
          bf_[ks_][i_] = *(const bf16x8*)(bs_ + ks_ * 4096 + (wn + i_ * 16 + fr) * 32 + slot_); \
        } } \
      __builtin_amdgcn_s_setprio(1); \
      _Pragma("unroll") \
      for (int i_ = 0; i_ < 4; ++i_) \
        _Pragma("unroll") \
        for (int j_ = 0; j_ < 4; ++j_) \
          acc[i_][j_] = __builtin_amdgcn_mfma_f32_16x16x32_bf16(af_[0][i_], bf_[0][j_], acc[i_][j_], 0, 0, 0); \
      __builtin_amdgcn_s_setprio(0); \
      bar_lds(); \
      if (t + 2 < (NTt)) PSTG(Amat, Bmat, t & 1); \
      __builtin_amdgcn_s_setprio(1); \
      _Pragma("unroll") \
      for (int i_ = 0; i_ < 4; ++i_) \
        _Pragma("unroll") \
        for (int j_ = 0; j_ < 4; ++j_) \
          acc[i_][j_] = __builtin_amdgcn_mfma_f32_16x16x32_bf16(af_[1][i_], bf_[1][j_], acc[i_][j_], 0, 0, 0); \
      __builtin_amdgcn_s_setprio(0); \
      __builtin_amdgcn_sched_barrier(0); \
      if (t + 2 < (NTt)) { asm volatile("s_waitcnt vmcnt(8)" ::: "memory"); } \
      else               { asm volatile("s_waitcnt vmcnt(0)" ::: "memory"); } \
      __builtin_amdgcn_s_barrier(); \
      __builtin_amdgcn_sched_barrier(0); \
    } } while (0)

// ---------------- generic pipelined GEMM (used for out-proj) ----------------
__global__ __launch_bounds__(256) void gemm_bt_bf16(
    const unsigned short* __restrict__ A, const unsigned short* __restrict__ BT,
    void* __restrict__ Cout, int M, int N, int K, int act)
{
  __shared__ unsigned short As[2][8192];
  __shared__ unsigned short Bs[2][8192];
  const int tid = threadIdx.x;
  const int bm = blockIdx.y * 128, bn = blockIdx.x * 128;
  const int lane = tid & 63, wave = tid >> 6;
  const int wm = (wave >> 1) * 64, wn = (wave & 1) * 64;
  const int fr = lane & 15, kq = lane >> 4;
  const int NT = K >> 6;

  f32x4 acc[4][4];
#pragma unroll
  for (int i = 0; i < 4; ++i)
#pragma unroll
    for (int j = 0; j < 4; ++j) acc[i][j] = (f32x4){0.f, 0.f, 0.f, 0.f};

  PGEMM_LOOP(As, Bs, A, BT, K, NT);

  if (act == 2) {
    unsigned short* C = (unsigned short*)Cout;
#pragma unroll
    for (int i = 0; i < 4; ++i) {
      int rbase = bm + wm + i * 16 + kq * 4;
#pragma unroll
      for (int r = 0; r < 4; ++r) {
        size_t rowoff = (size_t)(rbase + r) * N + bn + wn + fr;
#pragma unroll
        for (int j = 0; j < 4; ++j) C[rowoff + j * 16] = f2bf(acc[i][j][r]);
      }
    }
  } else {
    float* C = (float*)Cout;
#pragma unroll
    for (int i = 0; i < 4; ++i) {
      int rbase = bm + wm + i * 16 + kq * 4;
#pragma unroll
      for (int r = 0; r < 4; ++r) {
        size_t rowoff = (size_t)(rbase + r) * N + bn + wn + fr;
#pragma unroll
        for (int j = 0; j < 4; ++j) {
          float v = acc[i][j][r];
          if (act == 1) v = silu_f(v);
          C[rowoff + j * 16] = v;
        }
      }
    }
  }
}

// ---------------- fused projection GEMM (pipelined, grouped 1D grid) ----------------
__global__ __launch_bounds__(256) void gemm_fused(
    const unsigned short* __restrict__ A, const unsigned short* __restrict__ BT,
    float* __restrict__ Cq, float* __restrict__ Ck, float* __restrict__ Cx,
    unsigned short* __restrict__ Cg, float* __restrict__ Ct)
{
  __shared__ unsigned short As[2][8192];
  __shared__ unsigned short Bs[2][8192];
  const int tid = threadIdx.x;
  const int NPN = NFUSE / 128;           // 74
  const int GROUP = 8;
  const int npig = GROUP * NPN;          // 592
  const int pid = blockIdx.x;
  const int gid = pid / npig;
  const int pm = gid * GROUP + (pid % GROUP);
  const int pn = (pid % npig) / GROUP;
  const int bm = pm * 128, bn = pn * 128;
  const int lane = tid & 63, wave = tid >> 6;
  const int wm = (wave >> 1) * 64, wn = (wave & 1) * 64;
  const int fr = lane & 15, kq = lane >> 4;
  const int NT = DIM >> 6;               // 32

  f32x4 acc[4][4];
#pragma unroll
  for (int i = 0; i < 4; ++i)
#pragma unroll
    for (int j = 0; j < 4; ++j) acc[i][j] = (f32x4){0.f, 0.f, 0.f, 0.f};

  PGEMM_LOOP(As, Bs, A, BT, DIM, NT);

  // segment resolve (block-uniform)
  float* Fd = nullptr; unsigned short* Bd = nullptr;
  int strideN, cb, mode;   // mode: 0=fp32, 1=silu fp32, 2=bf16
  if (bn < 1536)      { Fd = Cq; strideN = 1536; cb = bn;        mode = 1; }
  else if (bn < 3072) { Fd = Ck; strideN = 1536; cb = bn - 1536; mode = 1; }
  else if (bn < 6144) { Fd = Cx; strideN = 3072; cb = bn - 3072; mode = 0; }
  else if (bn < 9216) { Bd = Cg; strideN = 3072; cb = bn - 6144; mode = 2; }
  else                { Fd = Ct; strideN = 256;  cb = bn - 9216; mode = 1; }

  if (mode == 2) {
#pragma unroll
    for (int i = 0; i < 4; ++i) {
      int rbase = bm + wm + i * 16 + kq * 4;
#pragma unroll
      for (int r = 0; r < 4; ++r) {
        size_t rowoff = (size_t)(rbase + r) * strideN + cb + wn + fr;
#pragma unroll
        for (int j = 0; j < 4; ++j) Bd[rowoff + j * 16] = f2bf(acc[i][j][r]);
      }
    }
  } else {
#pragma unroll
    for (int i = 0; i < 4; ++i) {
      int rbase = bm + wm + i * 16 + kq * 4;
#pragma unroll
      for (int r = 0; r < 4; ++r) {
        size_t rowoff = (size_t)(rbase + r) * strideN + cb + wn + fr;
#pragma unroll
        for (int j = 0; j < 4; ++j) {
          float v = acc[i][j][r];
          if (mode == 1) v = silu_f(v);
          Fd[rowoff + j * 16] = v;
        }
      }
    }
  }
}

// ---------------- dyn = tg @ gen_w2 ----------------
__global__ __launch_bounds__(256) void proj_dyn(
    const float* __restrict__ tg, const float* __restrict__ w2, float* __restrict__ dyn)
{
  int t = blockIdx.x, tid = threadIdx.x;
  float g = tg[(size_t)t * 256 + tid];
  float p[4];
#pragma unroll
  for (int j = 0; j < 4; ++j) p[j] = g * w2[tid * 4 + j];
#pragma unroll
  for (int j = 0; j < 4; ++j)
    for (int m = 32; m >= 1; m >>= 1) p[j] += __shfl_xor(p[j], m);
  __shared__ float red[4][4];
  if ((tid & 63) == 0) {
    int w = tid >> 6;
#pragma unroll
    for (int j = 0; j < 4; ++j) red[w][j] = p[j];
  }
  __syncthreads();
  if (tid < 4) dyn[(size_t)t * 4 + tid] = red[0][tid] + red[1][tid] + red[2][tid] + red[3][tid];
}

// ---------------- beta / raw decay log-gate g ----------------
__global__ __launch_bounds__(256) void proj_bg(
    const float* __restrict__ h, const float* __restrict__ Wb, const float* __restrict__ Wa,
    const float* __restrict__ A_log, const float* __restrict__ dt_bias,
    float* __restrict__ beta, float* __restrict__ gout)
{
  int t = blockIdx.x, tid = threadIdx.x;
  float pb[6], pa[6];
#pragma unroll
  for (int j = 0; j < 6; ++j) { pb[j] = 0.f; pa[j] = 0.f; }
  for (int d = tid; d < DIM; d += 256) {
    float hv = h[(size_t)t * DIM + d];
#pragma unroll
    for (int j = 0; j < 6; ++j) {
      pb[j] += hv * Wb[d * 6 + j];
      pa[j] += hv * Wa[d * 6 + j];
    }
  }
#pragma unroll
  for (int j = 0; j < 6; ++j)
    for (int m = 32; m >= 1; m >>= 1) { pb[j] += __shfl_xor(pb[j], m); pa[j] += __shfl_xor(pa[j], m); }
  __shared__ float rb[4][6], ra[4][6];
  if ((tid & 63) == 0) {
    int w = tid >> 6;
#pragma unroll
    for (int j = 0; j < 6; ++j) { rb[w][j] = pb[j]; ra[w][j] = pa[j]; }
  }
  __syncthreads();
  if (tid < 6) {
    int j = tid;
    float sb = rb[0][j] + rb[1][j] + rb[2][j] + rb[3][j];
    float sa = ra[0][j] + ra[1][j] + ra[2][j] + ra[3][j];
    beta[(size_t)t * 6 + j] = 1.f / (1.f + expf(-sb));
    float z = sa + dt_bias[j];
    float sp = (z > 20.f) ? z : log1pf(expf(z));
    gout[(size_t)t * 6 + j] = -expf(A_log[j]) * sp;   // raw log-gate (g < 0)
  }
}

// ---------------- causal dynamic conv + silu (8 timesteps/thread) ----------------
__global__ __launch_bounds__(256) void conv_kernel(
    const float* __restrict__ x, const float* __restrict__ dyn,
    const float* __restrict__ cw, float* __restrict__ v)
{
  int c = blockIdx.x * 256 + threadIdx.x;
  int t0 = blockIdx.y * 8;
  float4 w4 = ((const float4*)cw)[c];
  float xs[11];
#pragma unroll
  for (int i = 0; i < 11; ++i) {
    int t = t0 - 3 + i;
    xs[i] = (t >= 0) ? x[(size_t)t * VD + c] : 0.f;
  }
#pragma unroll
  for (int j = 0; j < 8; ++j) {
    int t = t0 + j;
    float4 dd = ((const float4*)dyn)[t];
    float acc = (w4.x + dd.x) * xs[j]
              + (w4.y + dd.y) * xs[j + 1]
              + (w4.z + dd.z) * xs[j + 2]
              + (w4.w + dd.w) * xs[j + 3];
    v[(size_t)t * VD + c] = silu_f(acc);
  }
}

// ---------------- P1: within-chunk inclusive cumsum of g, gamma = exp(c_end) ----------------
__global__ __launch_bounds__(64) void cumsum_g(
    const float* __restrict__ g, float* __restrict__ c, float* __restrict__ gammas)
{
  int ch = blockIdx.x, h = blockIdx.y;
  int t0 = ch * CK;
  int lane = threadIdx.x;
  float cum = g[(size_t)(t0 + lane) * 6 + h];
  for (int off = 1; off < 64; off <<= 1) {
    float n = __shfl_up(cum, off);
    if (lane >= off) cum += n;
  }
  c[(size_t)h * T_LEN + t0 + lane] = cum;
  if (lane == 63) gammas[h * NCHK + ch] = __expf(cum);
}

// ---------------- fused l2norm + Kbar/Qbar scale ----------------
__global__ __launch_bounds__(384) void l2scale(
    float* __restrict__ q, float* __restrict__ k, const float* __restrict__ c,
    unsigned short* __restrict__ Qb, unsigned short* __restrict__ Kb)
{
  int t = blockIdx.x;
  int h = threadIdx.x >> 6, lane = threadIdx.x & 63;
  size_t off = (size_t)t * KD + h * 256 + lane * 4;
  float4 qv = *(const float4*)(q + off);
  float4 kv = *(const float4*)(k + off);
  float sq = qv.x*qv.x + qv.y*qv.y + qv.z*qv.z + qv.w*qv.w;
  float sk = kv.x*kv.x + kv.y*kv.y + kv.z*kv.z + kv.w*kv.w;
  for (int m = 32; m >= 1; m >>= 1) { sq += __shfl_xor(sq, m); sk += __shfl_xor(sk, m); }
  float rq = rsqrtf(sq + 1e-6f) * 0.0625f;   // fold DK^-0.5
  float rk = rsqrtf(sk + 1e-6f);
  qv.x *= rq; qv.y *= rq; qv.z *= rq; qv.w *= rq;
  kv.x *= rk; kv.y *= rk; kv.z *= rk; kv.w *= rk;
  *(float4*)(q + off) = qv;
  *(float4*)(k + off) = kv;
  float w1 = __expf(c[(size_t)h * T_LEN + t]);
  ushort4 qo, ko;
  qo.x = f2bf(w1 * qv.x); qo.y = f2bf(w1 * qv.y); qo.z = f2bf(w1 * qv.z); qo.w = f2bf(w1 * qv.w);
  ko.x = f2bf(w1 * kv.x); ko.y = f2bf(w1 * kv.y); ko.z = f2bf(w1 * kv.z); ko.w = f2bf(w1 * kv.w);
  *(ushort4*)(Qb + off) = qo;
  *(ushort4*)(Kb + off) = ko;
}

// ---------------- P2b: KhT[h][ch][kk][tt] = exp(c_end - c_t) * k[t][kk]  (bf16) ----------------
// LDS-transpose form (R9): coalesced loads -> [64][258] tile -> coalesced writes.
__global__ __launch_bounds__(256) void make_khT(
    const float* __restrict__ k, const float* __restrict__ c,
    unsigned short* __restrict__ KhT)
{
  int ch = blockIdx.x, h = blockIdx.y;
  int t0 = ch * CK;
  int tid = threadIdx.x;
  __shared__ unsigned short tile[64][258];
  __shared__ float ws[64];
  if (tid < 64) {
    float cend = c[(size_t)h * T_LEN + t0 + 63];
    ws[tid] = __expf(cend - c[(size_t)h * T_LEN + t0 + tid]);
  }
  __syncthreads();
#pragma unroll 8
  for (int rr = 0; rr < 64; ++rr) {
    float kv = k[(size_t)(t0 + rr) * KD + h * 256 + tid];
    tile[rr][tid] = f2bf(ws[rr] * kv);
  }
  __syncthreads();
  size_t obase = ((size_t)(h * NCHK + ch)) * DK * CK;
  int tt = tid & 63, kr = tid >> 6;
#pragma unroll 8
  for (int kb = 0; kb < 64; ++kb) {
    int kk = kb * 4 + kr;
    KhT[obase + (size_t)kk * CK + tt] = tile[tt][kk];
  }
}

// ---------------- P3: per (h,chunk): L, P via MFMA ----------------
__global__ __launch_bounds__(256) void chunk_lp(
    const float* __restrict__ q, const float* __restrict__ k,
    const float* __restrict__ c, const float* __restrict__ beta,
    float* __restrict__ Lg, unsigned short* __restrict__ Pm)
{
  const int ch = blockIdx.x, h = blockIdx.y;
  const int t0 = ch * CK;
  const int tid = threadIdx.x;
  const int w = tid >> 6, lane = tid & 63, fr = lane & 15, kq = lane >> 4;
  __shared__ unsigned short kb[64][264];
  __shared__ unsigned short qb[64][264];
  __shared__ float cs[64], bs[64];
#pragma unroll
  for (int i = 0; i < 16; ++i) {
    int fi = tid + i * 256;
    int r = fi >> 6, d4 = fi & 63;
    float4 kv = *(const float4*)(k + (size_t)(t0 + r) * KD + h * 256 + d4 * 4);
    float4 qv = *(const float4*)(q + (size_t)(t0 + r) * KD + h * 256 + d4 * 4);
    ushort4 k4, q4;
    k4.x = f2bf(kv.x); k4.y = f2bf(kv.y); k4.z = f2bf(kv.z); k4.w = f2bf(kv.w);
    q4.x = f2bf(qv.x); q4.y = f2bf(qv.y); q4.z = f2bf(qv.z); q4.w = f2bf(qv.w);
    *(ushort4*)&kb[r][d4 * 4] = k4;
    *(ushort4*)&qb[r][d4 * 4] = q4;
  }
  if (tid < 64) {
    cs[tid] = c[(size_t)h * T_LEN + t0 + tid];
    bs[tid] = beta[(size_t)(t0 + tid) * 6 + h];
  }
  __syncthreads();

  f32x4 akk[4], aqk[4];
#pragma unroll
  for (int j = 0; j < 4; ++j) { akk[j] = (f32x4){0,0,0,0}; aqk[j] = (f32x4){0,0,0,0}; }
#pragma unroll
  for (int kt = 0; kt < 8; ++kt) {
    bf16x8 ak = *(const bf16x8*)&kb[16 * w + fr][kt * 32 + kq * 8];
    bf16x8 aq = *(const bf16x8*)&qb[16 * w + fr][kt * 32 + kq * 8];
#pragma unroll
    for (int j = 0; j < 4; ++j) {
      bf16x8 b = *(const bf16x8*)&kb[j * 16 + fr][kt * 32 + kq * 8];
      akk[j] = __builtin_amdgcn_mfma_f32_16x16x32_bf16(ak, b, akk[j], 0, 0, 0);
      aqk[j] = __builtin_amdgcn_mfma_f32_16x16x32_bf16(aq, b, aqk[j], 0, 0, 0);
    }
  }
  size_t base = ((size_t)(h * NCHK + ch)) * CK * CK;
#pragma unroll
  for (int j = 0; j < 4; ++j) {
#pragma unroll
    for (int r = 0; r < 4; ++r) {
      int t = 16 * w + kq * 4 + r, col = j * 16 + fr;
      float e = __expf(fminf(cs[t] - cs[col], 0.f));
      Lg[base + t * 64 + col] = (col < t) ? bs[t] * e * akk[j][r] : 0.f;
      Pm[base + t * 64 + col] = f2bf((col <= t) ? e * aqk[j][r] : 0.f);
    }
  }
}

// ---------------- P4: T' = (I+L)^{-1} diag(beta)  (bf16) ----------------
__global__ __launch_bounds__(64) void tri_inv(
    const float* __restrict__ Lg, const float* __restrict__ beta,
    unsigned short* __restrict__ Tm)
{
  const int ch = blockIdx.x, h = blockIdx.y;
  const size_t base = ((size_t)(h * NCHK + ch)) * CK * CK;
  const int j = threadIdx.x;
  __shared__ float Ll[64][65];
  __shared__ float Tl[64][65];
  for (int t = 0; t < 64; ++t) Ll[t][j] = Lg[base + t * 64 + j];
  __syncthreads();
  for (int t = 0; t < 64; ++t) {
    float s;
    if (j > t) s = 0.f;
    else if (j == t) s = 1.f;
    else {
      s = 0.f;
      for (int m = j; m < t; ++m) s -= Ll[t][m] * Tl[m][j];
    }
    Tl[t][j] = s;
  }
  float bj = beta[(size_t)(ch * 64 + j) * 6 + h];
  for (int t = 0; t < 64; ++t) Tm[base + t * 64 + j] = f2bf(Tl[t][j] * bj);
}

// ---------------- chunked gated delta-rule scan (MFMA, 8-wave) — R3 form ----------------
__global__ __launch_bounds__(512, 2) void scan_chunk(
    const unsigned short* __restrict__ Kb,   // [T][KD] Kbar
    const unsigned short* __restrict__ Qb,   // [T][KD] Qbar
    const unsigned short* __restrict__ KhT,  // [H][NCHK][DK][CK]
    const unsigned short* __restrict__ Tm,   // [H][NCHK][CK][CK]
    const unsigned short* __restrict__ Pm,   // [H][NCHK][CK][CK]
    const float* __restrict__ gammas,        // [H][NCHK]
    float* __restrict__ VO)                  // [T][VD]: V in, O out (in place)
{
  const int h = blockIdx.y, sl = blockIdx.x;
  const int tid = threadIdx.x;
  const int w = tid >> 6, lane = tid & 63;
  const int tw = w & 3, kg = w >> 2;
  const int fr = lane & 15, kq = lane >> 4;

  __shared__ unsigned short S0h[16][264];
  __shared__ unsigned short S0l[16][264];
  __shared__ unsigned short XT[16][72];
  __shared__ unsigned short DVT[16][72];
  __shared__ float PY[2][4][16][20];   // partial Y, [kg][tw][fr][kq*4+r]
  __shared__ float PO[2][4][16][20];   // partial O

  f32x4 st[2];
  st[0] = (f32x4){0.f, 0.f, 0.f, 0.f};
  st[1] = (f32x4){0.f, 0.f, 0.f, 0.f};

  const int colg = h * DVh + sl * 16 + fr;
  const size_t hc0 = (size_t)h * NCHK;

  // zero-init S0 staging (cols 0..255 are the ones read)
  {
    int zr = tid >> 5;          // 0..15
    int zc = (tid & 31) * 8;    // 0..248
    ushort4 z; z.x = 0; z.y = 0; z.z = 0; z.w = 0;
    *(ushort4*)&S0h[zr][zc]     = z;
    *(ushort4*)&S0h[zr][zc + 4] = z;
    *(ushort4*)&S0l[zr][zc]     = z;
    *(ushort4*)&S0l[zr][zc + 4] = z;
  }

  bf16x8 kfA[4], kfB[4], qfA[4], qfB[4];
  float vlA[4], vlB[4];

#define PREF(KF, QF, VL, chn) do { \
    const unsigned short* kr_ = Kb + (size_t)((chn) * CK + 16 * tw + fr) * KD + h * 256 + kg * 128 + kq * 8; \
    const unsigned short* qr_ = Qb + (size_t)((chn) * CK + 16 * tw + fr) * KD + h * 256 + kg * 128 + kq * 8; \
    _Pragma("unroll") \
    for (int kt = 0; kt < 4; ++kt) { \
      KF[kt] = *(const bf16x8*)(kr_ + kt * 32); \
      QF[kt] = *(const bf16x8*)(qr_ + kt * 32); } \
    if (kg == 0) { \
      _Pragma("unroll") \
      for (int r = 0; r < 4; ++r) VL[r] = VO[(size_t)((chn) * CK + 16 * tw + kq * 4 + r) * VD + colg]; } \
  } while (0)

#define BODY(chx, KF, QF, VL, KFN, QFN, VLN) do { \
    const int ch_ = (chx); \
    const int t0_ = ch_ * CK; \
    const size_t cb_ = hc0 + ch_; \
    /* tpf: kg0 = T' rows (for DV), kg1 = P rows (for O) */ \
    bf16x8 tpf[2]; \
    { const unsigned short* b_ = (kg == 0 ? Tm : Pm) + (cb_ * CK + 16 * tw + fr) * CK + kq * 8; \
      tpf[0] = *(const bf16x8*)(b_); tpf[1] = *(const bf16x8*)(b_ + 32); } \
    bf16x8 hfr[2][2]; \
    _Pragma("unroll") \
    for (int i = 0; i < 2; ++i) { \
      const unsigned short* hr_ = KhT + (cb_ * DK + 32 * w + 16 * i + fr) * CK + kq * 8; \
      hfr[i][0] = *(const bf16x8*)(hr_); hfr[i][1] = *(const bf16x8*)(hr_ + 32); } \
    const float gam_ = gammas[cb_]; \
    { const int chn_ = (ch_ + 1 < NCHK) ? ch_ + 1 : ch_; PREF(KFN, QFN, VLN, chn_); } \
    /* P1: partial Y/O over this wave's half of DK (4 kt) */ \
    f32x4 yt, ot; \
    { f32x4 yh = (f32x4){0.f,0.f,0.f,0.f}, yl = yh, oh = yh, ol = yh; \
      __builtin_amdgcn_s_setprio(1); \
      _Pragma("unroll") \
      for (int kt = 0; kt < 4; ++kt) { \
        const int ka_ = (kg * 4 + kt) * 32 + kq * 8; \
        bf16x8 bh_ = *(const bf16x8*)&S0h[fr][ka_]; \
        bf16x8 bl_ = *(const bf16x8*)&S0l[fr][ka_]; \
        yh = __builtin_amdgcn_mfma_f32_16x16x32_bf16(KF[kt], bh_, yh, 0, 0, 0); \
        yl = __builtin_amdgcn_mfma_f32_16x16x32_bf16(KF[kt], bl_, yl, 0, 0, 0); \
        oh = __builtin_amdgcn_mfma_f32_16x16x32_bf16(QF[kt], bh_, oh, 0, 0, 0); \
        ol = __builtin_amdgcn_mfma_f32_16x16x32_bf16(QF[kt], bl_, ol, 0, 0, 0); } \
      __builtin_amdgcn_s_setprio(0); \
      yt = yh + yl; ot = oh + ol; } \
    *(f32x4*)&PY[kg][tw][fr][kq * 4] = yt; \
    *(f32x4*)&PO[kg][tw][fr][kq * 4] = ot; \
    bar_lds();   /* B1: partials visible */ \
    if (kg == 0) { \
      f32x4 yo = *(const f32x4*)&PY[1][tw][fr][kq * 4]; \
      ushort4 x4; \
      x4.x = f2bf(VL[0] - (yt[0] + yo[0])); \
      x4.y = f2bf(VL[1] - (yt[1] + yo[1])); \
      x4.z = f2bf(VL[2] - (yt[2] + yo[2])); \
      x4.w = f2bf(VL[3] - (yt[3] + yo[3])); \
      *(ushort4*)&XT[fr][16 * tw + kq * 4] = x4; \
    } else { \
      f32x4 oo = *(const f32x4*)&PO[0][tw][fr][kq * 4]; \
      ot[0] += oo[0]; ot[1] += oo[1]; ot[2] += oo[2]; ot[3] += oo[3]; } \
    bar_lds();   /* B2: XT visible */ \
    /* P2: DV = T' X (kg0 only) */ \
    if (kg == 0) { \
      f32x4 d = (f32x4){0.f,0.f,0.f,0.f}; \
      bf16x8 b0_ = *(const bf16x8*)&XT[fr][kq * 8]; \
      bf16x8 b1_ = *(const bf16x8*)&XT[fr][32 + kq * 8]; \
      d = __builtin_amdgcn_mfma_f32_16x16x32_bf16(tpf[0], b0_, d, 0, 0, 0); \
      d = __builtin_amdgcn_mfma_f32_16x16x32_bf16(tpf[1], b1_, d, 0, 0, 0); \
      ushort4 d4; \
      d4.x = f2bf(d[0]); d4.y = f2bf(d[1]); d4.z = f2bf(d[2]); d4.w = f2bf(d[3]); \
      *(ushort4*)&DVT[fr][16 * tw + kq * 4] = d4; } \
    bar_lds();   /* B3: DVT visible */ \
    /* P3: O-store (kg1), state update + S0 staging (all) */ \
    { bf16x8 dv0_ = *(const bf16x8*)&DVT[fr][kq * 8]; \
      bf16x8 dv1_ = *(const bf16x8*)&DVT[fr][32 + kq * 8]; \
      if (kg == 1) { \
        f32x4 op = (f32x4){0.f,0.f,0.f,0.f}; \
        op = __builtin_amdgcn_mfma_f32_16x16x32_bf16(tpf[0], dv0_, op, 0, 0, 0); \
        op = __builtin_amdgcn_mfma_f32_16x16x32_bf16(tpf[1], dv1_, op, 0, 0, 0); \
        _Pragma("unroll") \
        for (int r = 0; r < 4; ++r) \
          VO[(size_t)(t0_ + 16 * tw + kq * 4 + r) * VD + colg] = ot[r] + op[r]; } \
      __builtin_amdgcn_s_setprio(1); \
      _Pragma("unroll") \
      for (int i = 0; i < 2; ++i) { \
        st[i][0] *= gam_; st[i][1] *= gam_; st[i][2] *= gam_; st[i][3] *= gam_; \
        st[i] = __builtin_amdgcn_mfma_f32_16x16x32_bf16(hfr[i][0], dv0_, st[i], 0, 0, 0); \
        st[i] = __builtin_amdgcn_mfma_f32_16x16x32_bf16(hfr[i][1], dv1_, st[i], 0, 0, 0); \
        ushort4 hi4, lo4; \
        { float s0 = st[i][0], s1 = st[i][1], s2 = st[i][2], s3 = st[i][3]; \
          hi4.x = f2bf(s0); lo4.x = f2bf(s0 - bf2f(hi4.x)); \
          hi4.y = f2bf(s1); lo4.y = f2bf(s1 - bf2f(hi4.y)); \
          hi4.z = f2bf(s2); lo4.z = f2bf(s2 - bf2f(hi4.z)); \
          hi4.w = f2bf(s3); lo4.w = f2bf(s3 - bf2f(hi4.w)); } \
        *(ushort4*)&S0h[fr][32 * w + 16 * i + kq * 4] = hi4; \
        *(ushort4*)&S0l[fr][32 * w + 16 * i + kq * 4] = lo4; } \
      __builtin_amdgcn_s_setprio(0); } \
    bar_lds();   /* B4: S0 visible for next chunk */ \
  } while (0)

  PREF(kfA, qfA, vlA, 0);
  __syncthreads();   // covers the LDS zero-init
  for (int ch = 0; ch < NCHK; ch += 2) {
    BODY(ch,     kfA, qfA, vlA, kfB, qfB, vlB);
    BODY(ch + 1, kfB, qfB, vlB, kfA, qfA, vlA);
  }
#undef BODY
#undef PREF
}

// ---------------- gated RMSNorm ----------------
__global__ __launch_bounds__(256) void norm_gate(
    const float* __restrict__ o, const unsigned short* __restrict__ gate,
    const float* __restrict__ nw, unsigned short* __restrict__ out)
{
  int th = blockIdx.x, tid = threadIdx.x;
  size_t base = (size_t)th * DVh;
  float x0 = o[base + tid], x1 = o[base + 256 + tid];
  float ss = x0 * x0 + x1 * x1;
  for (int m = 32; m >= 1; m >>= 1) ss += __shfl_xor(ss, m);
  __shared__ float red[4];
  if ((tid & 63) == 0) red[tid >> 6] = ss;
  __syncthreads();
  float rms = rsqrtf((red[0] + red[1] + red[2] + red[3]) * (1.f / 512.f) + 1e-5f);
  float g0 = bf2f(gate[base + tid]), g1 = bf2f(gate[base + 256 + tid]);
  out[base + tid]       = f2bf(x0 * rms * nw[tid]       * silu_f(g0));
  out[base + 256 + tid] = f2bf(x1 * rms * nw[tid + 256] * silu_f(g1));
}

extern "C" void kernel_launch(void* const* d_in, const int* in_sizes, int n_in,
                              void* d_out, int out_size, void* d_ws, size_t ws_size,
                              hipStream_t stream)
{
  const float* h       = (const float*)d_in[0];
  const float* Wq      = (const float*)d_in[1];
  const float* Wk      = (const float*)d_in[2];
  const float* Wv      = (const float*)d_in[3];
  const float* Wb      = (const float*)d_in[4];
  const float* Wa      = (const float*)d_in[5];
  const float* Wg      = (const float*)d_in[6];
  const float* Wo      = (const float*)d_in[7];
  const float* A_log   = (const float*)d_in[8];
  const float* dt_bias = (const float*)d_in[9];
  const float* conv_w  = (const float*)d_in[10];
  const float* gen_w1  = (const float*)d_in[11];
  const float* gen_w2  = (const float*)d_in[12];
  const float* norm_w  = (const float*)d_in[13];
  float* out = (float*)d_out;

  const size_t TK = (size_t)T_LEN * KD, TV = (size_t)T_LEN * VD, TD = (size_t)T_LEN * DIM;

  float* ws   = (float*)d_ws;
  float* q    = ws;
  float* k    = q    + TK;
  float* x    = k    + TK;          // h@Wv conv input; region later reused (see aliases)
  float* v    = x    + TV;          // conv out; O written in place by scan
  float* tg   = v    + TV;          // T*256
  float* dyn  = tg   + (size_t)T_LEN * 256;
  float* beta = dyn  + (size_t)T_LEN * 4;
  float* g    = beta + (size_t)T_LEN * 6;
  float* c    = g    + (size_t)T_LEN * 6;       // [H][T]
  float* gam  = c    + (size_t)NH * T_LEN;      // [H][NCHK]
  float* fend = gam  + 512;
  unsigned short* bh      = (unsigned short*)fend;          // T*DIM
  unsigned short* wT      = bh      + TD;                   // DIM*VD (used for Wo only)
  unsigned short* gate_bf = wT      + (size_t)DIM * VD;     // T*VD
  unsigned short* go_bf   = gate_bf + TV;                   // T*VD
  // aliases (lifetime-disjoint):
  unsigned short* Kb_s  = bh;                 // Kbar: bh dead after fused GEMM
  unsigned short* Qb_s  = (unsigned short*)x; // x region free after conv
  unsigned short* KhT_s = Qb_s + TK;
  unsigned short* Tm_s  = KhT_s + TK;         // H*NCHK*DK*CK == T*KD
  unsigned short* Pm_s  = Tm_s + (size_t)NH * NCHK * CK * CK;
  float* Lg = (float*)go_bf;                  // consumed before norm_gate writes go_bf
  // stacked B^T for fused GEMM: [9472][2048] bf16 = 38.8 MB; aliases v region
  // (50.3 MB) — used only before conv_kernel writes v.
  unsigned short* wTall = (unsigned short*)v;

  dim3 blk(256);
  cast_bf16<<<(TD / 4) / 256, blk, 0, stream>>>(h, bh);
  // ALL weight transposes (5 stacked projections + Wo) in one launch
  tcast_all<<<25088, blk, 0, stream>>>(Wq, Wk, Wv, Wg, gen_w1, Wo, wTall, wT);
  // one fused GEMM for q | k | x | gate | tg (1D grid, grouped block order)
  gemm_fused<<<dim3((NFUSE / 128) * (T_LEN / 128)), blk, 0, stream>>>(
      bh, wTall, q, k, x, gate_bf, tg);

  proj_bg<<<T_LEN, blk, 0, stream>>>(h, Wb, Wa, A_log, dt_bias, beta, g);
  cumsum_g<<<dim3(NCHK, NH), 64, 0, stream>>>(g, c, gam);
  proj_dyn<<<T_LEN, blk, 0, stream>>>(tg, gen_w2, dyn);
  conv_kernel<<<dim3(VD / 256, T_LEN / 8), blk, 0, stream>>>(x, dyn, conv_w, v);
  l2scale<<<T_LEN, 384, 0, stream>>>(q, k, c, Qb_s, Kb_s);

  make_khT<<<dim3(NCHK, NH), blk, 0, stream>>>(k, c, KhT_s);
  chunk_lp<<<dim3(NCHK, NH), blk, 0, stream>>>(q, k, c, beta, Lg, Pm_s);
  tri_inv<<<dim3(NCHK, NH), 64, 0, stream>>>(Lg, beta, Tm_s);

  scan_chunk<<<dim3(DVh / 16, NH), 512, 0, stream>>>(Kb_s, Qb_s, KhT_s, Tm_s, Pm_s, gam, v);

  norm_gate<<<T_LEN * NH, blk, 0, stream>>>(v, gate_bf, norm_w, go_bf);
  gemm_bt_bf16<<<dim3(DIM / 128, T_LEN / 128), blk, 0, stream>>>(go_bf, wT, out, T_LEN, DIM, VD, 0);
}